// Round 1
// baseline (213.572 us; speedup 1.0000x reference)
//
#include <hip/hip_runtime.h>
#include <cstdint>

// Problem constants (from reference)
constexpr int B     = 16384;
constexpr int NNEG  = 10;
constexpr int D     = 8;
constexpr int E     = 64;               // 64 floats = 256B per table row
constexpr int ROWS  = B * (1 + NNEG);   // 180224; flat row id == output index
constexpr int RPW   = 4;                // rows per wave per batch (one per 16-lane group)
constexpr int NB    = 4;                // pipelined batches per wave (double-buffered)
constexpr int WPB   = 2;                // waves per 128-thread block
constexpr int BATCH_BYTES    = D * 1024;          // 8 KB per batch (8 DMA x 1KB)
constexpr int LDS_PER_WAVE   = 2 * BATCH_BYTES;   // 16 KB: 2-deep pipeline
constexpr int ROWS_PER_WAVE  = RPW * NB;          // 16
constexpr int ROWS_PER_BLOCK = WPB * ROWS_PER_WAVE; // 32

// pair_sum = sum_{i<j} e_i.e_j = 0.5*(||sum_d e_d||^2 - sum_d ||e_d||^2).
//
// Round theory: previous version was latency-bound (1.74 TB/s effective on
// random 256B gathers) because each wave did issue-8KB -> vmcnt(0) drain ->
// __syncthreads -> exit: near-zero average outstanding bytes per CU.
// This version: no barrier (waves touch only their own LDS region), 4 batches
// per wave, double-buffered, counted vmcnt(8) waits so 8-16KB stays in flight
// per wave continuously. In-order vmcnt retire makes vmcnt(8) safe: batch k+1's
// 8 DMAs are always newer than batch k's in the FIFO, so <=8 outstanding
// implies batch k fully deposited (stores between batches only ADD to the
// count, which keeps the wait conservative).
__device__ __forceinline__ void dma16(const float* gp, void* lp) {
    __builtin_amdgcn_global_load_lds(
        (const __attribute__((address_space(1))) void*)gp,
        (__attribute__((address_space(3))) void*)lp,
        16, 0, 0);
}

__global__ __launch_bounds__(128) void APE_61555471286335_kernel(
    const int*   __restrict__ pos_x,   // [B, D]
    const int*   __restrict__ neg_x,   // [B, NNEG, D]
    const float* __restrict__ emb,     // [N_ENT, E]
    const float* __restrict__ pair_w,  // [N_PAIRS]
    const float* __restrict__ c,       // [1]
    float*       __restrict__ out)     // [ROWS]
{
    __shared__ char smem[WPB * LDS_PER_WAVE];   // 32 KB/block -> 5 blocks/CU

    const int lane = threadIdx.x & 63;
    const int wid  = threadIdx.x >> 6;          // wave within block
    const int wave = blockIdx.x * WPB + wid;
    const int g    = lane >> 4;                 // output row within batch (0..3)
    const int t    = lane & 15;                 // quad: dims [4t, 4t+4)
    const int rowBase = wave * ROWS_PER_WAVE + g;   // batch k -> rowBase + k*RPW

    char* base = smem + wid * LDS_PER_WAVE;     // wave-private region

    // All NB batches' indices up front: these VMEM loads retire before the
    // counted-wait window opens, so they never perturb the vmcnt arithmetic.
    int id[NB][D];
#pragma unroll
    for (int k = 0; k < NB; ++k) {
        const int row = rowBase + k * RPW;
        const int* ip = (row < B) ? (pos_x + (size_t)row * D)
                                  : (neg_x + (size_t)(row - B) * D);
        const int4 a = ((const int4*)ip)[0];
        const int4 b = ((const int4*)ip)[1];
        id[k][0] = a.x; id[k][1] = a.y; id[k][2] = a.z; id[k][3] = a.w;
        id[k][4] = b.x; id[k][5] = b.y; id[k][6] = b.z; id[k][7] = b.w;
    }

    // Scalar params: materialize before the DMA window (s_load path, but pin
    // anyway so nothing sinks into the counted region).
    float sc = expf(pair_w[0]);
    float c0 = c[0];
    asm volatile("" : "+v"(sc), "+v"(c0));

    // Prologue: batch 0 into buffer 0. Deposit rule: base + d*1024 + lane*16
    // == base + d*1024 + g*256 + t*16 (row g's quad t), matching HW's
    // wave-uniform-base + lane*size layout.
#pragma unroll
    for (int d = 0; d < D; ++d)
        dma16(emb + (size_t)id[0][d] * E + t * 4,
              base + d * 1024 + lane * 16);

#pragma unroll
    for (int k = 0; k < NB; ++k) {
        if (k + 1 < NB) {
            // Issue batch k+1 BEFORE waiting on batch k: keeps >=8KB in flight.
            char* nbuf = base + ((k + 1) & 1) * BATCH_BYTES;
#pragma unroll
            for (int d = 0; d < D; ++d)
                dma16(emb + (size_t)id[k + 1][d] * E + t * 4,
                      nbuf + d * 1024 + lane * 16);
            __builtin_amdgcn_s_waitcnt(0x0f78);   // vmcnt(8): batch k deposited
        } else {
            __builtin_amdgcn_s_waitcnt(0x0f70);   // vmcnt(0): final drain
        }
        asm volatile("" ::: "memory");            // no LDS read hoists past wait

        const char* bk = base + (k & 1) * BATCH_BYTES;
        float4 s = make_float4(0.f, 0.f, 0.f, 0.f), q = s;
#pragma unroll
        for (int d = 0; d < D; ++d) {
            const float4 v = *(const float4*)(bk + d * 1024 + lane * 16);
            s.x += v.x; s.y += v.y; s.z += v.z; s.w += v.w;
            q.x += v.x * v.x; q.y += v.y * v.y;
            q.z += v.z * v.z; q.w += v.w * v.w;
        }
        float p = s.x * s.x + s.y * s.y + s.z * s.z + s.w * s.w
                - (q.x + q.y + q.z + q.w);

        // Butterfly within each 16-lane group (offsets < 16 stay in-group).
#pragma unroll
        for (int off = 8; off > 0; off >>= 1)
            p += __shfl_xor(p, off, 64);

        if (t == 0)
            out[rowBase + k * RPW] = expf(0.5f * p * sc + c0);
    }
}

extern "C" void kernel_launch(void* const* d_in, const int* in_sizes, int n_in,
                              void* d_out, int out_size, void* d_ws, size_t ws_size,
                              hipStream_t stream) {
    const int*   pos_x  = (const int*)  d_in[0];
    const int*   neg_x  = (const int*)  d_in[1];
    const float* emb    = (const float*)d_in[2];
    const float* pair_w = (const float*)d_in[3];
    const float* c      = (const float*)d_in[4];
    float*       out    = (float*)      d_out;

    constexpr int BLOCK = WPB * 64;             // 128
    static_assert(ROWS % ROWS_PER_BLOCK == 0, "exact grid");
    const int grid = ROWS / ROWS_PER_BLOCK;     // 5632

    APE_61555471286335_kernel<<<grid, BLOCK, 0, stream>>>(
        pos_x, neg_x, emb, pair_w, c, out);
}